// Round 1
// baseline (1592.258 us; speedup 1.0000x reference)
//
#include <hip/hip_runtime.h>
#include <hip/hip_bf16.h>

#define TT 2048
#define BB 8
#define DD 1024
#define HH 16
#define NNd 32
#define FF 2048   // 4*H*N
#define HN 512

// ---------- fast math helpers ----------
__device__ __forceinline__ float fexp2(float x){
#if __has_builtin(__builtin_amdgcn_exp2f)
    return __builtin_amdgcn_exp2f(x);
#else
    return exp2f(x);
#endif
}
__device__ __forceinline__ float frcp(float x){
#if __has_builtin(__builtin_amdgcn_rcpf)
    return __builtin_amdgcn_rcpf(x);
#else
    return 1.0f / x;
#endif
}
__device__ __forceinline__ float fsqrt_(float x){
#if __has_builtin(__builtin_amdgcn_sqrtf)
    return __builtin_amdgcn_sqrtf(x);
#else
    return sqrtf(x);
#endif
}
__device__ __forceinline__ float fast_tanh(float x){
    // tanh(x) = 1 - 2/(exp(2x)+1); robust at +-inf (exp2 -> inf/0)
    float e = fexp2(2.88539008f * x);
    return 1.0f - 2.0f * frcp(e + 1.0f);
}
__device__ __forceinline__ float fast_sigmoid(float x){
    return frcp(1.0f + fexp2(-1.44269504f * x));
}

// DPP-based add of lane (this ^ pattern). All-VALU, no DS ops.
template<int CTRL>
__device__ __forceinline__ float dppadd(float v){
#if __has_builtin(__builtin_amdgcn_update_dpp)
    int x = __builtin_amdgcn_update_dpp(0, __float_as_int(v), CTRL, 0xf, 0xf, true);
    return v + __int_as_float(x);
#else
    int m = (CTRL == 0xB1) ? 1 : (CTRL == 0x4E) ? 2 : 4;
    return v + __shfl_xor(v, m);
#endif
}
// sum over 8-lane group (lanes l & ~7 .. |7), result in all 8 lanes
__device__ __forceinline__ float reduce8(float v){
    v = dppadd<0xB1>(v);   // quad_perm [1,0,3,2]  : + lane^1
    v = dppadd<0x4E>(v);   // quad_perm [2,3,0,1]  : + lane^2
    v = dppadd<0x141>(v);  // row_half_mirror      : + other quad (uniform by now)
    return v;
}

// ---------- concat the 4 projection weights into [2048,1024] ----------
__global__ __launch_bounds__(256)
void concat4(const float* __restrict__ s0, const float* __restrict__ s1,
             const float* __restrict__ s2, const float* __restrict__ s3,
             float* __restrict__ dst)
{
    size_t i = (size_t)blockIdx.x * 256 + threadIdx.x;  // float4 index
    const size_t q = (size_t)HN * DD / 4;               // 131072 float4 per matrix
    const float* s = (i < q) ? s0 : (i < 2*q) ? s1 : (i < 3*q) ? s2 : s3;
    size_t off = i & (q - 1);
    ((float4*)dst)[i] = ((const float4*)s)[off];
}

// ---------- fp32 tiled GEMM: C[m,n] = sum_k A[m,k] * (BT ? B[n,k] : B[k,n]) ----------
// BM=BN=128, BK=16, 256 threads, 8x8 per thread. EPI: sigmoid(+bias) on cols >= 1536.
template<bool BT, bool EPI>
__global__ __launch_bounds__(256)
void gemm_tile(const float* __restrict__ A, const float* __restrict__ B,
               float* __restrict__ C, int M, int N, int K,
               const float* __restrict__ bias)
{
    __shared__ __align__(16) float As[16][132];
    __shared__ __align__(16) float Bs[16][144];   // gapped: float4 col c at word 4*(c + c/8)
    const int tid = threadIdx.x;
    const int tx = tid & 15, ty = tid >> 4;
    const int n0 = blockIdx.x * 128, m0 = blockIdx.y * 128;
    float acc[8][8] = {};

    for (int k0 = 0; k0 < K; k0 += 16) {
        #pragma unroll
        for (int rr = 0; rr < 2; ++rr) {
            int idx = tid + rr * 256;
            int row = idx >> 2, c4 = (idx & 3) << 2;
            float4 v = *(const float4*)&A[(size_t)(m0 + row) * K + k0 + c4];
            As[c4+0][row] = v.x; As[c4+1][row] = v.y;
            As[c4+2][row] = v.z; As[c4+3][row] = v.w;
        }
        if (BT) {
            #pragma unroll
            for (int rr = 0; rr < 2; ++rr) {
                int idx = tid + rr * 256;
                int row = idx >> 2, c4 = (idx & 3) << 2;      // row = n-index
                float4 v = *(const float4*)&B[(size_t)(n0 + row) * K + k0 + c4];
                int w = row + ((row >> 5) << 2);              // gapped scalar position
                Bs[c4+0][w] = v.x; Bs[c4+1][w] = v.y;
                Bs[c4+2][w] = v.z; Bs[c4+3][w] = v.w;
            }
        } else {
            #pragma unroll
            for (int rr = 0; rr < 2; ++rr) {
                int idx = tid + rr * 256;
                int kk = idx >> 5, c = idx & 31;
                float4 v = *(const float4*)&B[(size_t)(k0 + kk) * N + n0 + (c << 2)];
                int p = c + (c >> 3);
                *(float4*)&Bs[kk][p << 2] = v;
            }
        }
        __syncthreads();
        #pragma unroll
        for (int kk = 0; kk < 16; ++kk) {
            float a[8], b[8];
            *(float4*)&a[0] = *(const float4*)&As[kk][ty * 8];
            *(float4*)&a[4] = *(const float4*)&As[kk][ty * 8 + 4];
            int c = tx * 2;
            int p = c + (c >> 3);
            *(float4*)&b[0] = *(const float4*)&Bs[kk][p << 2];
            *(float4*)&b[4] = *(const float4*)&Bs[kk][(p + 1) << 2];
            #pragma unroll
            for (int i = 0; i < 8; ++i)
                #pragma unroll
                for (int j = 0; j < 8; ++j)
                    acc[i][j] += a[i] * b[j];
        }
        __syncthreads();
    }

    #pragma unroll
    for (int ii = 0; ii < 8; ++ii) {
        int m = m0 + ty * 8 + ii;
        float* crow = &C[(size_t)m * N + n0 + tx * 8];
        #pragma unroll
        for (int jj = 0; jj < 2; ++jj) {
            float4 v;
            v.x = acc[ii][jj*4+0]; v.y = acc[ii][jj*4+1];
            v.z = acc[ii][jj*4+2]; v.w = acc[ii][jj*4+3];
            if (EPI) {
                int n = n0 + tx * 8 + jj * 4;
                if (n >= 3 * HN) {   // beta block: sigmoid(x + bias)
                    int bi = n - 3 * HN;
                    v.x = fast_sigmoid(v.x + bias[bi+0]);
                    v.y = fast_sigmoid(v.y + bias[bi+1]);
                    v.z = fast_sigmoid(v.z + bias[bi+2]);
                    v.w = fast_sigmoid(v.w + bias[bi+3]);
                }
            }
            *(float4*)&crow[jj * 4] = v;
        }
    }
}

// ---------- sequential recurrence ----------
// 256 blocks x 128 threads. Block bx: chain bh = bx>>1, rows (bx&1)*16 .. +15.
// Thread: row i = rbase + (tid>>3), owns j = (tid&7)*4 .. +3. State in registers.
// Reductions over j are over 8 lanes -> reduce8 (pure DPP). No LDS, no barriers.
__global__ __launch_bounds__(128)
void recur(const float* __restrict__ proj, const float* __restrict__ S0,
           float* __restrict__ out, float* __restrict__ Sfin)
{
    const int bx = blockIdx.x;
    const int bh = bx >> 1;
    const int b  = bh >> 4, h = bh & 15;
    const int tid = threadIdx.x;
    const int i  = ((bx & 1) << 4) + (tid >> 3);  // row 0..31
    const int js = tid & 7;

    float S[4];
    {
        const float* s0 = S0 + (size_t)bh * 1024 + i * 32 + js * 4;
        S[0] = s0[0]; S[1] = s0[1]; S[2] = s0[2]; S[3] = s0[3];
    }

    const size_t rowstep = (size_t)BB * FF;               // 16384 floats per t
    const float* pk = proj + (size_t)b * FF + h * 32 + js * 4;
    const float* pq = pk + 2 * HN;                        // q block at +1024
    const float* pv = proj + (size_t)b * FF + HN + h * 32 + i;
    const float* pb = pv + 2 * HN;                        // beta block at +1024 from v
    float* po = out + (size_t)b * HN + h * 32 + i;

    float4 k4 = *(const float4*)pk;
    float4 q4 = *(const float4*)pq;
    float vi = *pv, bi = *pb;

    for (int t = 0; t < TT; ++t) {
        // prefetch t+1 (clamped)
        size_t nxt = (size_t)((t + 1 < TT) ? t + 1 : t) * rowstep;
        float4 k4n = *(const float4*)(pk + nxt);
        float4 q4n = *(const float4*)(pq + nxt);
        float vin = *(pv + nxt), bin = *(pb + nxt);

        // ||k|| over j
        float ss = k4.x*k4.x + k4.y*k4.y + k4.z*k4.z + k4.w*k4.w;
        ss = reduce8(ss);
        float rn = frcp(fsqrt_(ss) + 1e-6f);
        float kn0 = k4.x * rn, kn1 = k4.y * rn, kn2 = k4.z * rn, kn3 = k4.w * rn;

        // retrieved_i = sum_j S[i,j] * kn[j]
        float r = S[0]*kn0 + S[1]*kn1 + S[2]*kn2 + S[3]*kn3;
        r = reduce8(r);
        float delta = vi - r;

        // S = tanh(beta_i * S + delta_i * kn_j)
        S[0] = fast_tanh(bi * S[0] + delta * kn0);
        S[1] = fast_tanh(bi * S[1] + delta * kn1);
        S[2] = fast_tanh(bi * S[2] + delta * kn2);
        S[3] = fast_tanh(bi * S[3] + delta * kn3);

        // Sq_i = sum_j S[i,j] * q[j]
        float sq = S[0]*q4.x + S[1]*q4.y + S[2]*q4.z + S[3]*q4.w;
        sq = reduce8(sq);

        if (js == 0) {
            float sg = fast_sigmoid(sq);
            po[(size_t)t * BB * HN] = sq * sq * sg;
        }
        k4 = k4n; q4 = q4n; vi = vin; bi = bin;
    }

    float* sf = Sfin + (size_t)bh * 1024 + i * 32 + js * 4;
    sf[0] = S[0]; sf[1] = S[1]; sf[2] = S[2]; sf[3] = S[3];
}

extern "C" void kernel_launch(void* const* d_in, const int* in_sizes, int n_in,
                              void* d_out, int out_size, void* d_ws, size_t ws_size,
                              hipStream_t stream) {
    const float* x      = (const float*)d_in[0];
    const float* S0     = (const float*)d_in[1];
    const float* W_in   = (const float*)d_in[2];
    const float* W_k    = (const float*)d_in[3];
    const float* W_v    = (const float*)d_in[4];
    const float* W_q    = (const float*)d_in[5];
    const float* W_beta = (const float*)d_in[6];
    const float* b_beta = (const float*)d_in[7];

    float* ws    = (float*)d_ws;
    float* Wxcat = ws;                                  // [2048,1024]   8 MB
    float* Weff  = ws + (size_t)FF * DD;                // [2048,1024]   8 MB
    float* proj  = ws + (size_t)2 * FF * DD;            // [16384,2048] 128 MB

    float* out_  = (float*)d_out;                       // [T,B,512]
    float* Sfin  = out_ + (size_t)TT * BB * HN;         // [B,H,N,N]

    // 1) concat weights
    concat4<<<dim3(2048), dim3(256), 0, stream>>>(W_k, W_v, W_q, W_beta, Wxcat);
    // 2) W_eff[f,d] = sum_e Wxcat[f,e] * W_in[e,d]   (B not transposed)
    gemm_tile<false,false><<<dim3(DD/128, FF/128), dim3(256), 0, stream>>>(
        Wxcat, W_in, Weff, FF, DD, DD, nullptr);
    // 3) proj[m,f] = sum_d x[m,d] * Weff[f,d]        (B transposed), sigmoid on beta cols
    gemm_tile<true,true><<<dim3(FF/128, (TT*BB)/128), dim3(256), 0, stream>>>(
        x, Weff, proj, TT*BB, FF, DD, b_beta);
    // 4) recurrence
    recur<<<dim3(256), dim3(128), 0, stream>>>(proj, S0, out_, Sfin);
}

// Round 2
// 1408.499 us; speedup vs baseline: 1.1305x; 1.1305x over previous
//
#include <hip/hip_runtime.h>
#include <hip/hip_bf16.h>
#include <stdint.h>

#define TT 2048
#define BB 8
#define DD 1024
#define FF 2048   // 4*H*N
#define HN 512
#define KB_CNT 32         // DD/32 k-blocks
#define ROWB 128          // bytes per (row, k-block): 8 slots * 16B (hi 4 + lo 4)
#define MSTRIDE 4096      // bytes per row in split layout = KB_CNT*ROWB
#define PF 8              // recurrence prefetch depth

typedef float f32x4 __attribute__((ext_vector_type(4)));
typedef _Float16 h8_t __attribute__((ext_vector_type(8)));

// ---------- fast math helpers ----------
__device__ __forceinline__ float fexp2(float x){ return __builtin_amdgcn_exp2f(x); }
__device__ __forceinline__ float frcp(float x){ return __builtin_amdgcn_rcpf(x); }
__device__ __forceinline__ float fsqrt_(float x){ return __builtin_amdgcn_sqrtf(x); }
__device__ __forceinline__ float fast_tanh(float x){
    float e = fexp2(2.88539008f * x);
    return 1.0f - 2.0f * frcp(e + 1.0f);
}
__device__ __forceinline__ float fast_sigmoid(float x){
    return frcp(1.0f + fexp2(-1.44269504f * x));
}

// DPP-based 8-lane reduction (pure VALU)
template<int CTRL>
__device__ __forceinline__ float dppadd(float v){
    int x = __builtin_amdgcn_update_dpp(0, __float_as_int(v), CTRL, 0xf, 0xf, true);
    return v + __int_as_float(x);
}
__device__ __forceinline__ float reduce8(float v){
    v = dppadd<0xB1>(v);   // + lane^1
    v = dppadd<0x4E>(v);   // + lane^2
    v = dppadd<0x141>(v);  // row_half_mirror: + other quad
    return v;
}

// ---------- concat the 4 projection weights into [2048,1024] ----------
__global__ __launch_bounds__(256)
void concat4(const float* __restrict__ s0, const float* __restrict__ s1,
             const float* __restrict__ s2, const float* __restrict__ s3,
             float* __restrict__ dst)
{
    size_t i = (size_t)blockIdx.x * 256 + threadIdx.x;
    const size_t q = (size_t)HN * DD / 4;
    const float* s = (i < q) ? s0 : (i < 2*q) ? s1 : (i < 3*q) ? s2 : s3;
    size_t off = i & (q - 1);
    ((float4*)dst)[i] = ((const float4*)s)[off];
}

// ---------- fp32 tiled GEMM (only for the tiny Weff product) ----------
__global__ __launch_bounds__(256)
void gemm_f32(const float* __restrict__ A, const float* __restrict__ B,
              float* __restrict__ C, int M, int N, int K)
{
    __shared__ __align__(16) float As[16][132];
    __shared__ __align__(16) float Bs[16][144];
    const int tid = threadIdx.x;
    const int tx = tid & 15, ty = tid >> 4;
    const int n0 = blockIdx.x * 128, m0 = blockIdx.y * 128;
    float acc[8][8] = {};
    for (int k0 = 0; k0 < K; k0 += 16) {
        #pragma unroll
        for (int rr = 0; rr < 2; ++rr) {
            int idx = tid + rr * 256;
            int row = idx >> 2, c4 = (idx & 3) << 2;
            float4 v = *(const float4*)&A[(size_t)(m0 + row) * K + k0 + c4];
            As[c4+0][row] = v.x; As[c4+1][row] = v.y;
            As[c4+2][row] = v.z; As[c4+3][row] = v.w;
        }
        #pragma unroll
        for (int rr = 0; rr < 2; ++rr) {
            int idx = tid + rr * 256;
            int kk = idx >> 5, c = idx & 31;
            float4 v = *(const float4*)&B[(size_t)(k0 + kk) * N + n0 + (c << 2)];
            int p = c + (c >> 3);
            *(float4*)&Bs[kk][p << 2] = v;
        }
        __syncthreads();
        #pragma unroll
        for (int kk = 0; kk < 16; ++kk) {
            float a[8], b[8];
            *(float4*)&a[0] = *(const float4*)&As[kk][ty * 8];
            *(float4*)&a[4] = *(const float4*)&As[kk][ty * 8 + 4];
            int c = tx * 2, p = c + (c >> 3);
            *(float4*)&b[0] = *(const float4*)&Bs[kk][p << 2];
            *(float4*)&b[4] = *(const float4*)&Bs[kk][(p + 1) << 2];
            #pragma unroll
            for (int i = 0; i < 8; ++i)
                #pragma unroll
                for (int j = 0; j < 8; ++j)
                    acc[i][j] += a[i] * b[j];
        }
        __syncthreads();
    }
    #pragma unroll
    for (int ii = 0; ii < 8; ++ii) {
        int m = m0 + ty * 8 + ii;
        float* crow = &C[(size_t)m * N + n0 + tx * 8];
        #pragma unroll
        for (int jj = 0; jj < 2; ++jj) {
            float4 v;
            v.x = acc[ii][jj*4+0]; v.y = acc[ii][jj*4+1];
            v.z = acc[ii][jj*4+2]; v.w = acc[ii][jj*4+3];
            *(float4*)&crow[jj * 4] = v;
        }
    }
}

// ---------- split fp32 -> (hi,lo) fp16, pre-swizzled layout ----------
// layout: [row][kb][slot 0..7][16B]; logical chunk c (0-3 hi k-chunks, 4-7 lo)
// stored at slot = c ^ (row & 7).
__device__ __forceinline__ void split8(const float* f, int4& hi, int4& lo){
    union { _Float16 h[8]; int4 i; } a, c;
    #pragma unroll
    for (int u = 0; u < 8; ++u) {
        _Float16 h = (_Float16)f[u];
        a.h[u] = h;
        c.h[u] = (_Float16)(f[u] - (float)h);
    }
    hi = a.i; lo = c.i;
}

__global__ __launch_bounds__(256)
void wconv(const float* __restrict__ W, char* __restrict__ out)
{
    int gid = blockIdx.x * 256 + threadIdx.x;   // 131072 threads total
    int n  = gid >> 6;          // row 0..2047
    int kh = gid & 63;          // 16-float segment
    const float* src = W + (size_t)n * DD + kh * 16;
    float f[16];
    *(float4*)&f[0]  = *(const float4*)(src + 0);
    *(float4*)&f[4]  = *(const float4*)(src + 4);
    *(float4*)&f[8]  = *(const float4*)(src + 8);
    *(float4*)&f[12] = *(const float4*)(src + 12);
    int4 hi0, hi1, lo0, lo1;
    split8(&f[0], hi0, lo0);
    split8(&f[8], hi1, lo1);
    int kb = kh >> 1, c0 = (kh & 1) * 2, rs = n & 7;
    char* dst = out + (size_t)n * MSTRIDE + kb * ROWB;
    *(int4*)(dst + (((c0+0) ^ rs) * 16)) = hi0;
    *(int4*)(dst + (((c0+1) ^ rs) * 16)) = hi1;
    *(int4*)(dst + (((c0+4) ^ rs) * 16)) = lo0;
    *(int4*)(dst + (((c0+5) ^ rs) * 16)) = lo1;
}

// ---------- fp16x2-split MFMA GEMM: proj[m,f] = sum_d x[m,d]*Weff[f,d] ----------
// 128x128 tile, BK=32, 256 threads (4 waves in 2x2). 3 MFMAs per fragment pair.
// B staged via global_load_lds from pre-swizzled wsplit; A reg-staged + converted.
__global__ __launch_bounds__(256)
void gemm_mfma(const float* __restrict__ A, const char* __restrict__ Wsp,
               float* __restrict__ C, const float* __restrict__ bias)
{
    __shared__ char lds[32768];
    char* Asb = lds;
    char* Bsb = lds + 16384;

    const int tid  = threadIdx.x;
    const int wave = tid >> 6, lane = tid & 63;
    const int wm = wave >> 1, wn = wave & 1;
    const int nt = blockIdx.x & 15, mt = blockIdx.x >> 4;
    const int m0 = mt * 128, n0 = nt * 128;

    f32x4 acc[4][4] = {};

    // A staging ids: thread covers row r, k-half kh (16 floats)
    const int ar = tid >> 1, akh = tid & 1, ars = ar & 7, ac0 = akh * 2;
    const float* asrc = A + (size_t)(m0 + ar) * DD + akh * 16;
    char* awr = Asb + ar * ROWB;

    // B staging: wave stages 8-row groups g = wave*4 .. +3
    const char* bsrc_base = Wsp + (size_t)n0 * MSTRIDE;

    // fragment read offsets (lane-static)
    const int fl = lane & 15, fh = lane >> 4;
    const int shi = (fh ^ (fl & 7)) * 16;
    const int slo = ((fh + 4) ^ (fl & 7)) * 16;
    const int frow = fl * ROWB;

    for (int ks = 0; ks < KB_CNT; ++ks) {
        // --- stage B (global_load_lds, pre-swizzled source) ---
        #pragma unroll
        for (int gg = 0; gg < 4; ++gg) {
            int g = wave * 4 + gg;
            const char* src = bsrc_base + (size_t)(g * 8 + (lane >> 3)) * MSTRIDE
                              + ks * ROWB + (lane & 7) * 16;
            __builtin_amdgcn_global_load_lds(
                (const __attribute__((address_space(1))) uint32_t*)src,
                (__attribute__((address_space(3))) uint32_t*)(Bsb + g * 1024),
                16, 0, 0);
        }
        // --- stage A (reg load fp32, split, swizzled ds_write) ---
        {
            const float* ap = asrc + ks * 32;
            float f[16];
            *(float4*)&f[0]  = *(const float4*)(ap + 0);
            *(float4*)&f[4]  = *(const float4*)(ap + 4);
            *(float4*)&f[8]  = *(const float4*)(ap + 8);
            *(float4*)&f[12] = *(const float4*)(ap + 12);
            int4 hi0, hi1, lo0, lo1;
            split8(&f[0], hi0, lo0);
            split8(&f[8], hi1, lo1);
            *(int4*)(awr + (((ac0+0) ^ ars) * 16)) = hi0;
            *(int4*)(awr + (((ac0+1) ^ ars) * 16)) = hi1;
            *(int4*)(awr + (((ac0+4) ^ ars) * 16)) = lo0;
            *(int4*)(awr + (((ac0+5) ^ ars) * 16)) = lo1;
        }
        __syncthreads();   // drains vmcnt (gload_lds) + lgkm (ds_write)

        // --- fragments + MFMA ---
        union { int4 i; h8_t h; } ah[4], al[4], bh[4], bl[4];
        #pragma unroll
        for (int fm = 0; fm < 4; ++fm) {
            const char* base = Asb + (wm * 64 + fm * 16) * ROWB + frow;
            ah[fm].i = *(const int4*)(base + shi);
            al[fm].i = *(const int4*)(base + slo);
        }
        #pragma unroll
        for (int fn = 0; fn < 4; ++fn) {
            const char* base = Bsb + (wn * 64 + fn * 16) * ROWB + frow;
            bh[fn].i = *(const int4*)(base + shi);
            bl[fn].i = *(const int4*)(base + slo);
        }
        #pragma unroll
        for (int fm = 0; fm < 4; ++fm)
            #pragma unroll
            for (int fn = 0; fn < 4; ++fn) {
                acc[fm][fn] = __builtin_amdgcn_mfma_f32_16x16x32_f16(ah[fm].h, bh[fn].h, acc[fm][fn], 0, 0, 0);
                acc[fm][fn] = __builtin_amdgcn_mfma_f32_16x16x32_f16(ah[fm].h, bl[fn].h, acc[fm][fn], 0, 0, 0);
                acc[fm][fn] = __builtin_amdgcn_mfma_f32_16x16x32_f16(al[fm].h, bh[fn].h, acc[fm][fn], 0, 0, 0);
            }
        __syncthreads();   // protect LDS before next-iter staging
    }

    // --- epilogue: C/D layout col=lane&15, row=(lane>>4)*4+reg ---
    const bool isbeta = (nt >= 12);
    #pragma unroll
    for (int fm = 0; fm < 4; ++fm) {
        int rbase = m0 + wm * 64 + fm * 16 + fh * 4;
        #pragma unroll
        for (int fn = 0; fn < 4; ++fn) {
            int col = n0 + wn * 64 + fn * 16 + fl;
            float bb = isbeta ? bias[col - 3 * HN] : 0.0f;
            #pragma unroll
            for (int reg = 0; reg < 4; ++reg) {
                float v = acc[fm][fn][reg];
                if (isbeta) v = fast_sigmoid(v + bb);
                C[(size_t)(rbase + reg) * FF + col] = v;
            }
        }
    }
}

// ---------- sequential recurrence, 8-deep register prefetch ----------
__global__ __launch_bounds__(128)
void recur(const float* __restrict__ proj, const float* __restrict__ S0,
           float* __restrict__ out, float* __restrict__ Sfin)
{
    const int bx = blockIdx.x;
    const int bh = bx >> 1;
    const int b  = bh >> 4, h = bh & 15;
    const int tid = threadIdx.x;
    const int i  = ((bx & 1) << 4) + (tid >> 3);
    const int js = tid & 7;

    float S[4];
    {
        const float* s0p = S0 + (size_t)bh * 1024 + i * 32 + js * 4;
        S[0]=s0p[0]; S[1]=s0p[1]; S[2]=s0p[2]; S[3]=s0p[3];
    }

    const size_t rowstep = (size_t)BB * FF;      // 16384 floats per t
    const float* pk = proj + (size_t)b * FF + h * 32 + js * 4;
    const float* pq = pk + 2 * HN;
    const float* pv = proj + (size_t)b * FF + HN + h * 32 + i;
    const float* pb = pv + 2 * HN;
    float* po = out + (size_t)b * HN + h * 32 + i;

    float4 kb[PF], qb[PF]; float vb[PF], bbf[PF];
    #pragma unroll
    for (int p = 0; p < PF; ++p) {
        kb[p] = *(const float4*)(pk + p * rowstep);
        qb[p] = *(const float4*)(pq + p * rowstep);
        vb[p] = pv[p * rowstep]; bbf[p] = pb[p * rowstep];
    }
    size_t off = (size_t)PF * rowstep;
    for (int t0 = 0; t0 < TT; t0 += PF) {
        #pragma unroll
        for (int p = 0; p < PF; ++p) {
            float4 k4 = kb[p], q4 = qb[p];
            float vi = vb[p], bi = bbf[p];
            if (t0 + PF + p < TT) {
                kb[p] = *(const float4*)(pk + off);
                qb[p] = *(const float4*)(pq + off);
                vb[p] = pv[off]; bbf[p] = pb[off];
            }
            off += rowstep;

            // parallel reductions: ||k||^2 and S.k
            float ss = k4.x*k4.x + k4.y*k4.y + k4.z*k4.z + k4.w*k4.w;
            float rr = S[0]*k4.x + S[1]*k4.y + S[2]*k4.z + S[3]*k4.w;
            ss = reduce8(ss); rr = reduce8(rr);
            float rn = frcp(fsqrt_(ss) + 1e-6f);
            float g  = rn * (vi - rr * rn);      // = delta * rn
            S[0] = fast_tanh(bi * S[0] + g * k4.x);
            S[1] = fast_tanh(bi * S[1] + g * k4.y);
            S[2] = fast_tanh(bi * S[2] + g * k4.z);
            S[3] = fast_tanh(bi * S[3] + g * k4.w);
            float sq = S[0]*q4.x + S[1]*q4.y + S[2]*q4.z + S[3]*q4.w;
            sq = reduce8(sq);
            if (js == 0) {
                float sg = fast_sigmoid(sq);
                po[(size_t)(t0 + p) * rowstep / 4] = sq * sq * sg;  // rowstep/4 = BB*HN
            }
        }
    }
    float* sf = Sfin + (size_t)bh * 1024 + i * 32 + js * 4;
    sf[0]=S[0]; sf[1]=S[1]; sf[2]=S[2]; sf[3]=S[3];
}

extern "C" void kernel_launch(void* const* d_in, const int* in_sizes, int n_in,
                              void* d_out, int out_size, void* d_ws, size_t ws_size,
                              hipStream_t stream) {
    const float* x      = (const float*)d_in[0];
    const float* S0     = (const float*)d_in[1];
    const float* W_in   = (const float*)d_in[2];
    const float* W_k    = (const float*)d_in[3];
    const float* W_v    = (const float*)d_in[4];
    const float* W_q    = (const float*)d_in[5];
    const float* W_beta = (const float*)d_in[6];
    const float* b_beta = (const float*)d_in[7];

    float* ws    = (float*)d_ws;
    float* proj  = ws;                            // 128 MB  [16384,2048] fp32
    float* Wxcat = ws + (size_t)33554432;         //   8 MB  [2048,1024] fp32
    float* Weff  = ws + (size_t)35651584;         //   8 MB  [2048,1024] fp32
    char*  wsplit= (char*)Wxcat;                  //   8 MB  overwrites Wxcat after use

    float* out_  = (float*)d_out;                 // [T,B,512]
    float* Sfin  = out_ + (size_t)TT * BB * HN;   // [B,H,N,N]

    // 1) concat weights
    concat4<<<dim3(2048), dim3(256), 0, stream>>>(W_k, W_v, W_q, W_beta, Wxcat);
    // 2) W_eff = Wxcat * W_in   (fp32, tiny)
    gemm_f32<<<dim3(DD/128, FF/128), dim3(256), 0, stream>>>(Wxcat, W_in, Weff, FF, DD, DD);
    // 3) split Weff -> fp16 hi/lo, pre-swizzled (overwrites Wxcat)
    wconv<<<dim3(512), dim3(256), 0, stream>>>(Weff, wsplit);
    // 4) proj = x * Weff^T via fp16x2-split MFMA (+ sigmoid/bias on beta cols)
    gemm_mfma<<<dim3(2048), dim3(256), 0, stream>>>(x, wsplit, proj, b_beta);
    // 5) recurrence
    recur<<<dim3(256), dim3(128), 0, stream>>>(proj, S0, out_, Sfin);
}

// Round 3
// 790.996 us; speedup vs baseline: 2.0130x; 1.7807x over previous
//
#include <hip/hip_runtime.h>
#include <hip/hip_bf16.h>
#include <stdint.h>

#define TT 2048
#define BB 8
#define DD 1024
#define FF 2048   // 4*H*N
#define HN 512
#define KB_CNT 32         // DD/32 k-blocks
#define ROWB 128          // bytes per (row, k-block): 8 slots * 16B
#define MSTRIDE 4096      // bytes per row in split layout = KB_CNT*ROWB
#define PF 8              // recurrence pipeline depth (8 steps * 4 loads = 32 in flight)

typedef float f32x4 __attribute__((ext_vector_type(4)));
typedef _Float16 h8_t __attribute__((ext_vector_type(8)));

// ---------- fast math helpers ----------
__device__ __forceinline__ float fexp2(float x){ return __builtin_amdgcn_exp2f(x); }
__device__ __forceinline__ float frcp(float x){ return __builtin_amdgcn_rcpf(x); }
__device__ __forceinline__ float fsqrt_(float x){ return __builtin_amdgcn_sqrtf(x); }
__device__ __forceinline__ float fast_tanh(float x){
    float e = fexp2(2.88539008f * x);
    return 1.0f - 2.0f * frcp(e + 1.0f);
}
__device__ __forceinline__ float fast_sigmoid(float x){
    return frcp(1.0f + fexp2(-1.44269504f * x));
}

// DPP-based 8-lane reduction (pure VALU)
template<int CTRL>
__device__ __forceinline__ float dppadd(float v){
    int x = __builtin_amdgcn_update_dpp(0, __float_as_int(v), CTRL, 0xf, 0xf, true);
    return v + __int_as_float(x);
}
__device__ __forceinline__ float reduce8(float v){
    v = dppadd<0xB1>(v);   // + lane^1
    v = dppadd<0x4E>(v);   // + lane^2
    v = dppadd<0x141>(v);  // row_half_mirror: + other quad
    return v;
}

// ---------- concat the 4 projection weights into [2048,1024] ----------
__global__ __launch_bounds__(256)
void concat4(const float* __restrict__ s0, const float* __restrict__ s1,
             const float* __restrict__ s2, const float* __restrict__ s3,
             float* __restrict__ dst)
{
    size_t i = (size_t)blockIdx.x * 256 + threadIdx.x;
    const size_t q = (size_t)HN * DD / 4;
    const float* s = (i < q) ? s0 : (i < 2*q) ? s1 : (i < 3*q) ? s2 : s3;
    size_t off = i & (q - 1);
    ((float4*)dst)[i] = ((const float4*)s)[off];
}

// ---------- fp32 tiled GEMM (only for the tiny Weff product) ----------
__global__ __launch_bounds__(256)
void gemm_f32(const float* __restrict__ A, const float* __restrict__ B,
              float* __restrict__ C, int M, int N, int K)
{
    __shared__ __align__(16) float As[16][132];
    __shared__ __align__(16) float Bs[16][144];
    const int tid = threadIdx.x;
    const int tx = tid & 15, ty = tid >> 4;
    const int n0 = blockIdx.x * 128, m0 = blockIdx.y * 128;
    float acc[8][8] = {};
    for (int k0 = 0; k0 < K; k0 += 16) {
        #pragma unroll
        for (int rr = 0; rr < 2; ++rr) {
            int idx = tid + rr * 256;
            int row = idx >> 2, c4 = (idx & 3) << 2;
            float4 v = *(const float4*)&A[(size_t)(m0 + row) * K + k0 + c4];
            As[c4+0][row] = v.x; As[c4+1][row] = v.y;
            As[c4+2][row] = v.z; As[c4+3][row] = v.w;
        }
        #pragma unroll
        for (int rr = 0; rr < 2; ++rr) {
            int idx = tid + rr * 256;
            int kk = idx >> 5, c = idx & 31;
            float4 v = *(const float4*)&B[(size_t)(k0 + kk) * N + n0 + (c << 2)];
            int p = c + (c >> 3);
            *(float4*)&Bs[kk][p << 2] = v;
        }
        __syncthreads();
        #pragma unroll
        for (int kk = 0; kk < 16; ++kk) {
            float a[8], b[8];
            *(float4*)&a[0] = *(const float4*)&As[kk][ty * 8];
            *(float4*)&a[4] = *(const float4*)&As[kk][ty * 8 + 4];
            int c = tx * 2, p = c + (c >> 3);
            *(float4*)&b[0] = *(const float4*)&Bs[kk][p << 2];
            *(float4*)&b[4] = *(const float4*)&Bs[kk][(p + 1) << 2];
            #pragma unroll
            for (int i = 0; i < 8; ++i)
                #pragma unroll
                for (int j = 0; j < 8; ++j)
                    acc[i][j] += a[i] * b[j];
        }
        __syncthreads();
    }
    #pragma unroll
    for (int ii = 0; ii < 8; ++ii) {
        int m = m0 + ty * 8 + ii;
        float* crow = &C[(size_t)m * N + n0 + tx * 8];
        #pragma unroll
        for (int jj = 0; jj < 2; ++jj) {
            float4 v;
            v.x = acc[ii][jj*4+0]; v.y = acc[ii][jj*4+1];
            v.z = acc[ii][jj*4+2]; v.w = acc[ii][jj*4+3];
            *(float4*)&crow[jj * 4] = v;
        }
    }
}

// ---------- split fp32 -> (hi,lo) fp16, pre-swizzled layout ----------
__device__ __forceinline__ void split8(const float* f, int4& hi, int4& lo){
    union { _Float16 h[8]; int4 i; } a, c;
    #pragma unroll
    for (int u = 0; u < 8; ++u) {
        _Float16 h = (_Float16)f[u];
        a.h[u] = h;
        c.h[u] = (_Float16)(f[u] - (float)h);
    }
    hi = a.i; lo = c.i;
}

__global__ __launch_bounds__(256)
void wconv(const float* __restrict__ W, char* __restrict__ out)
{
    int gid = blockIdx.x * 256 + threadIdx.x;
    int n  = gid >> 6;
    int kh = gid & 63;
    const float* src = W + (size_t)n * DD + kh * 16;
    float f[16];
    *(float4*)&f[0]  = *(const float4*)(src + 0);
    *(float4*)&f[4]  = *(const float4*)(src + 4);
    *(float4*)&f[8]  = *(const float4*)(src + 8);
    *(float4*)&f[12] = *(const float4*)(src + 12);
    int4 hi0, hi1, lo0, lo1;
    split8(&f[0], hi0, lo0);
    split8(&f[8], hi1, lo1);
    int kb = kh >> 1, c0 = (kh & 1) * 2, rs = n & 7;
    char* dst = out + (size_t)n * MSTRIDE + kb * ROWB;
    *(int4*)(dst + (((c0+0) ^ rs) * 16)) = hi0;
    *(int4*)(dst + (((c0+1) ^ rs) * 16)) = hi1;
    *(int4*)(dst + (((c0+4) ^ rs) * 16)) = lo0;
    *(int4*)(dst + (((c0+5) ^ rs) * 16)) = lo1;
}

// ---------- fp16x2-split MFMA GEMM (unchanged from R2) ----------
__global__ __launch_bounds__(256)
void gemm_mfma(const float* __restrict__ A, const char* __restrict__ Wsp,
               float* __restrict__ C, const float* __restrict__ bias)
{
    __shared__ char lds[32768];
    char* Asb = lds;
    char* Bsb = lds + 16384;

    const int tid  = threadIdx.x;
    const int wave = tid >> 6, lane = tid & 63;
    const int wm = wave >> 1, wn = wave & 1;
    const int nt = blockIdx.x & 15, mt = blockIdx.x >> 4;
    const int m0 = mt * 128, n0 = nt * 128;

    f32x4 acc[4][4] = {};

    const int ar = tid >> 1, akh = tid & 1, ars = ar & 7, ac0 = akh * 2;
    const float* asrc = A + (size_t)(m0 + ar) * DD + akh * 16;
    char* awr = Asb + ar * ROWB;

    const char* bsrc_base = Wsp + (size_t)n0 * MSTRIDE;

    const int fl = lane & 15, fh = lane >> 4;
    const int shi = (fh ^ (fl & 7)) * 16;
    const int slo = ((fh + 4) ^ (fl & 7)) * 16;
    const int frow = fl * ROWB;

    for (int ks = 0; ks < KB_CNT; ++ks) {
        #pragma unroll
        for (int gg = 0; gg < 4; ++gg) {
            int g = wave * 4 + gg;
            const char* src = bsrc_base + (size_t)(g * 8 + (lane >> 3)) * MSTRIDE
                              + ks * ROWB + (lane & 7) * 16;
            __builtin_amdgcn_global_load_lds(
                (const __attribute__((address_space(1))) uint32_t*)src,
                (__attribute__((address_space(3))) uint32_t*)(Bsb + g * 1024),
                16, 0, 0);
        }
        {
            const float* ap = asrc + ks * 32;
            float f[16];
            *(float4*)&f[0]  = *(const float4*)(ap + 0);
            *(float4*)&f[4]  = *(const float4*)(ap + 4);
            *(float4*)&f[8]  = *(const float4*)(ap + 8);
            *(float4*)&f[12] = *(const float4*)(ap + 12);
            int4 hi0, hi1, lo0, lo1;
            split8(&f[0], hi0, lo0);
            split8(&f[8], hi1, lo1);
            *(int4*)(awr + (((ac0+0) ^ ars) * 16)) = hi0;
            *(int4*)(awr + (((ac0+1) ^ ars) * 16)) = hi1;
            *(int4*)(awr + (((ac0+4) ^ ars) * 16)) = lo0;
            *(int4*)(awr + (((ac0+5) ^ ars) * 16)) = lo1;
        }
        __syncthreads();

        union { int4 i; h8_t h; } ah[4], al[4], bh[4], bl[4];
        #pragma unroll
        for (int fm = 0; fm < 4; ++fm) {
            const char* base = Asb + (wm * 64 + fm * 16) * ROWB + frow;
            ah[fm].i = *(const int4*)(base + shi);
            al[fm].i = *(const int4*)(base + slo);
        }
        #pragma unroll
        for (int fn = 0; fn < 4; ++fn) {
            const char* base = Bsb + (wn * 64 + fn * 16) * ROWB + frow;
            bh[fn].i = *(const int4*)(base + shi);
            bl[fn].i = *(const int4*)(base + slo);
        }
        #pragma unroll
        for (int fm = 0; fm < 4; ++fm)
            #pragma unroll
            for (int fn = 0; fn < 4; ++fn) {
                acc[fm][fn] = __builtin_amdgcn_mfma_f32_16x16x32_f16(ah[fm].h, bh[fn].h, acc[fm][fn], 0, 0, 0);
                acc[fm][fn] = __builtin_amdgcn_mfma_f32_16x16x32_f16(ah[fm].h, bl[fn].h, acc[fm][fn], 0, 0, 0);
                acc[fm][fn] = __builtin_amdgcn_mfma_f32_16x16x32_f16(al[fm].h, bh[fn].h, acc[fm][fn], 0, 0, 0);
            }
        __syncthreads();
    }

    const bool isbeta = (nt >= 12);
    #pragma unroll
    for (int fm = 0; fm < 4; ++fm) {
        int rbase = m0 + wm * 64 + fm * 16 + fh * 4;
        #pragma unroll
        for (int fn = 0; fn < 4; ++fn) {
            int col = n0 + wn * 64 + fn * 16 + fl;
            float bb = isbeta ? bias[col - 3 * HN] : 0.0f;
            #pragma unroll
            for (int reg = 0; reg < 4; ++reg) {
                float v = acc[fm][fn][reg];
                if (isbeta) v = fast_sigmoid(v + bb);
                C[(size_t)(rbase + reg) * FF + col] = v;
            }
        }
    }
}

// ---------- sequential recurrence: asm-pipelined loads, counted vmcnt ----------
// 256 blocks x 128 threads. Chain bh = bx>>1, rows (bx&1)*16..+15.
// Thread: row i, j-slot js (4 j's). 8-slot rotating register pipeline:
// 4 loads/step (k:dwordx4, q:dwordx4, v:dword, b:dword), 28-32 in flight,
// s_waitcnt vmcnt(24) guarantees steps t and t+1. Values are data-threaded
// through the waitcnt asm ("+v") so consumers cannot be hoisted above it.
// ||k||^2 -> rn for step t+1 is computed during step t (off the S-chain).
__global__ __launch_bounds__(128)
void recur(const float* __restrict__ proj, const float* __restrict__ S0,
           float* __restrict__ out, float* __restrict__ Sfin)
{
    const int bx = blockIdx.x;
    const int bh = bx >> 1;
    const int b  = bh >> 4, h = bh & 15;
    const int tid = threadIdx.x;
    const int i  = ((bx & 1) << 4) + (tid >> 3);
    const int js = tid & 7;

    float S[4];
    {
        const float* s0p = S0 + (size_t)bh * 1024 + i * 32 + js * 4;
        S[0]=s0p[0]; S[1]=s0p[1]; S[2]=s0p[2]; S[3]=s0p[3];
    }

    const size_t rowstep = (size_t)BB * FF;      // 16384 floats per t
    const float* pk = proj + (size_t)b * FF + h * 32 + js * 4;
    const float* pq = pk + 2 * HN;
    const float* pv = proj + (size_t)b * FF + HN + h * 32 + i;
    const float* pb = pv + 2 * HN;
    float* pot = out + (size_t)b * HN + h * 32 + i;

    f32x4 K[PF], Q[PF];
    float V[PF], Bt[PF];

    // prologue: issue PF steps (4 loads each, in order k,q,v,b)
    #pragma unroll
    for (int p = 0; p < PF; ++p) {
        asm volatile("global_load_dwordx4 %0, %1, off" : "=v"(K[p])  : "v"(pk + p * rowstep));
        asm volatile("global_load_dwordx4 %0, %1, off" : "=v"(Q[p])  : "v"(pq + p * rowstep));
        asm volatile("global_load_dword %0, %1, off"   : "=v"(V[p])  : "v"(pv + p * rowstep));
        asm volatile("global_load_dword %0, %1, off"   : "=v"(Bt[p]) : "v"(pb + p * rowstep));
    }

    // prime rn for step 0 (wait for step 0's 4 loads: 32 -> 28 outstanding)
    asm volatile("s_waitcnt vmcnt(28)" : "+v"(K[0]));
    float rn_cur;
    {
        float ss = K[0][0]*K[0][0] + K[0][1]*K[0][1] + K[0][2]*K[0][2] + K[0][3]*K[0][3];
        ss = reduce8(ss);
        rn_cur = frcp(fsqrt_(ss) + 1e-6f);
    }

    size_t off8 = (size_t)PF * rowstep;   // float offset of step t+PF
    for (int t0 = 0; t0 < TT; t0 += PF) {
        #pragma unroll
        for (int p = 0; p < PF; ++p) {
            const int t = t0 + p;
            const int pn = (p + 1) & (PF - 1);
            // wait: guarantees step t (slot p) and step t+1 (slot pn) complete.
            asm volatile("s_waitcnt vmcnt(24)"
                : "+v"(K[p]), "+v"(Q[p]), "+v"(V[p]), "+v"(Bt[p]), "+v"(K[pn]));
            f32x4 k4 = K[p], q4 = Q[p];
            float vi = V[p], bi = Bt[p];
            f32x4 kn = K[pn];

            // issue step t+PF into slot p (clamped to last row)
            asm volatile("global_load_dwordx4 %0, %1, off" : "=v"(K[p])  : "v"(pk + off8));
            asm volatile("global_load_dwordx4 %0, %1, off" : "=v"(Q[p])  : "v"(pq + off8));
            asm volatile("global_load_dword %0, %1, off"   : "=v"(V[p])  : "v"(pv + off8));
            asm volatile("global_load_dword %0, %1, off"   : "=v"(Bt[p]) : "v"(pb + off8));
            if (t + PF < TT - 1) off8 += rowstep;

            // S-chain: dot(S,k) -> reduce8 -> g -> tanh
            float rr = S[0]*k4[0] + S[1]*k4[1] + S[2]*k4[2] + S[3]*k4[3];
            float s2 = kn[0]*kn[0] + kn[1]*kn[1] + kn[2]*kn[2] + kn[3]*kn[3];
            rr = reduce8(rr);
            s2 = reduce8(s2);
            float g = rn_cur * (vi - rr * rn_cur);
            S[0] = fast_tanh(bi * S[0] + g * k4[0]);
            S[1] = fast_tanh(bi * S[1] + g * k4[1]);
            S[2] = fast_tanh(bi * S[2] + g * k4[2]);
            S[3] = fast_tanh(bi * S[3] + g * k4[3]);
            float rn_next = frcp(fsqrt_(s2) + 1e-6f);   // off the S-chain

            float sq = S[0]*q4[0] + S[1]*q4[1] + S[2]*q4[2] + S[3]*q4[3];
            sq = reduce8(sq);
            if (js == 0) {
                float sg = fast_sigmoid(sq);
                pot[(size_t)t * (BB * HN)] = sq * sq * sg;
            }
            rn_cur = rn_next;
        }
    }

    float* sf = Sfin + (size_t)bh * 1024 + i * 32 + js * 4;
    sf[0]=S[0]; sf[1]=S[1]; sf[2]=S[2]; sf[3]=S[3];
}

extern "C" void kernel_launch(void* const* d_in, const int* in_sizes, int n_in,
                              void* d_out, int out_size, void* d_ws, size_t ws_size,
                              hipStream_t stream) {
    const float* x      = (const float*)d_in[0];
    const float* S0     = (const float*)d_in[1];
    const float* W_in   = (const float*)d_in[2];
    const float* W_k    = (const float*)d_in[3];
    const float* W_v    = (const float*)d_in[4];
    const float* W_q    = (const float*)d_in[5];
    const float* W_beta = (const float*)d_in[6];
    const float* b_beta = (const float*)d_in[7];

    float* ws    = (float*)d_ws;
    float* proj  = ws;                            // 128 MB  [16384,2048] fp32
    float* Wxcat = ws + (size_t)33554432;         //   8 MB  [2048,1024] fp32
    float* Weff  = ws + (size_t)35651584;         //   8 MB  [2048,1024] fp32
    char*  wsplit= (char*)Wxcat;                  //   8 MB  overwrites Wxcat after use

    float* out_  = (float*)d_out;                 // [T,B,512]
    float* Sfin  = out_ + (size_t)TT * BB * HN;   // [B,H,N,N]

    concat4<<<dim3(2048), dim3(256), 0, stream>>>(W_k, W_v, W_q, W_beta, Wxcat);
    gemm_f32<<<dim3(DD/128, FF/128), dim3(256), 0, stream>>>(Wxcat, W_in, Weff, FF, DD, DD);
    wconv<<<dim3(512), dim3(256), 0, stream>>>(Weff, wsplit);
    gemm_mfma<<<dim3(2048), dim3(256), 0, stream>>>(x, wsplit, proj, b_beta);
    recur<<<dim3(256), dim3(128), 0, stream>>>(proj, S0, out_, Sfin);
}